// Round 13
// baseline (904.423 us; speedup 1.0000x reference)
//
#include <hip/hip_runtime.h>
#include <hip/hip_bf16.h>
#include <math.h>

#define BB 16
#define NN 2048

typedef __attribute__((ext_vector_type(8))) short s8v;
typedef __attribute__((ext_vector_type(4))) float f4v;

__global__ void k_sentinel(float* o, int n, float v){
  int i = blockIdx.x*256 + threadIdx.x;
  if (i < n) o[i] = v;
}

__device__ __forceinline__ ushort f2bf(float x){
  unsigned u = __float_as_uint(x);
  unsigned r = u + 0x7FFFu + ((u>>16)&1u);
  return (ushort)(r>>16);
}
__device__ __forceinline__ void splitbf(float v, ushort &h, ushort &l){
  h = f2bf(v);
  float hf = __uint_as_float((unsigned)h<<16);
  l = f2bf(v-hf);
}

/* ---------------- weight pre-split ---------------- */

__global__ void k_wsplit3h(const float* __restrict__ s1, ushort* __restrict__ d1h, int n1,
                           const float* __restrict__ s2, ushort* __restrict__ d2h, int n2,
                           const float* __restrict__ s3, ushort* __restrict__ d3h, int n3){
  int id = blockIdx.x*256 + threadIdx.x;
  const float* s; ushort *dh; int i;
  if (id < n1){ s=s1; dh=d1h; i=id; }
  else if (id < n1+n2){ s=s2; dh=d2h; i=id-n1; }
  else if (id < n1+n2+n3){ s=s3; dh=d3h; i=id-n1-n2; }
  else return;
  dh[i] = f2bf(s[i]);
}

__global__ void k_wstr4(const float* __restrict__ s1, ushort* __restrict__ d1h, ushort* __restrict__ d1l, int K1, int C1,
                        const float* __restrict__ s2, ushort* __restrict__ d2h, ushort* __restrict__ d2l, int K2, int C2,
                        const float* __restrict__ s3, ushort* __restrict__ d3h, ushort* __restrict__ d3l, int K3, int C3,
                        const float* __restrict__ s4, ushort* __restrict__ d4h, ushort* __restrict__ d4l, int K4, int C4){
  int id = blockIdx.x*256 + threadIdx.x;
  int n1=K1*C1, n2=K2*C2, n3=K3*C3, n4=K4*C4;
  const float* s; ushort *dh, *dl; int i, K, C;
  if (id < n1){ s=s1; dh=d1h; dl=d1l; i=id; K=K1; C=C1; }
  else if (id < n1+n2){ s=s2; dh=d2h; dl=d2l; i=id-n1; K=K2; C=C2; }
  else if (id < n1+n2+n3){ s=s3; dh=d3h; dl=d3l; i=id-n1-n2; K=K3; C=C3; }
  else if (id < n1+n2+n3+n4){ s=s4; dh=d4h; dl=d4l; i=id-n1-n2-n3; K=K4; C=C4; }
  else return;
  int c = i % C, k = i / C;
  ushort h,l; splitbf(s[i], h, l);
  dh[(size_t)c*K + k]=h; dl[(size_t)c*K + k]=l;
}

/* ---------------- MLP branch ---------------- */

__global__ void k_mlp1s(const float* __restrict__ xyz, const float* __restrict__ w1,
                        const float* __restrict__ b1, ushort* __restrict__ xh,
                        ushort* __restrict__ xl){
  int id = blockIdx.x*256 + threadIdx.x;
  if (id >= BB*NN*64) return;
  int o = id & 63, n = (id>>6) & (NN-1), b = id>>17;
  float acc = b1[o];
  #pragma unroll
  for (int c=0;c<3;c++)
    acc += w1[o*3+c] * xyz[(size_t)(b*3+c)*NN + n];
  acc = fmaxf(acc, 0.f);
  ushort h,l; splitbf(acc, h, l);
  xh[id]=h; xl[id]=l;
}

__global__ void k_gmax(const float* __restrict__ pmax, ushort* __restrict__ gh,
                       ushort* __restrict__ gl, int parts, int total){
  int id = blockIdx.x*256 + threadIdx.x;
  if (id >= total) return;
  float m = pmax[(size_t)id*parts];
  for (int k=1;k<parts;k++) m = fmaxf(m, pmax[(size_t)id*parts+k]);
  ushort h,l; splitbf(m, h, l);
  gh[id]=h; gl[id]=l;
}

/* ---------------- 2-pass split-bf16 MFMA GEMM body ---------------- */
template<int EPI, int RELU, int BCOL>
__device__ __forceinline__ void bgemm_body(
    const ushort* __restrict__ Ahg,
    const ushort* __restrict__ Bhg, const ushort* __restrict__ Blg,
    const ushort* __restrict__ gfh, const ushort* __restrict__ gfl,
    const float* __restrict__ bias,
    float* __restrict__ outp, float* __restrict__ pmaxp,
    ushort* __restrict__ oth, ushort* __restrict__ otl,
    int K, int ksplit, int Kb, int N, size_t sBT, size_t sOut, int M,
    int bx, int by, int bz, int nparts)
{
  __shared__ ushort Ah[128][40];
  __shared__ ushort Bh[64][40], Bl[64][40];
  __shared__ float red[2][128];
  int t = threadIdx.x, z = bz;
  int o0 = by*128, n0 = bx*64;
  int wid = t>>6, lane = t&63;
  int wm = wid>>1, wn = wid&1;
  int lr = lane&15, kg = lane>>4;

  f4v acc[4][2];
  #pragma unroll
  for (int i=0;i<4;i++)
    #pragma unroll
    for (int j=0;j<2;j++) acc[i][j] = (f4v){0.f,0.f,0.f,0.f};

  for (int k0=0; k0<K; k0+=32){
    __syncthreads();
    #pragma unroll
    for (int i=0;i<2;i++){
      int j = i*256+t, oo = j>>2, k8 = (j&3)*8;
      size_t sp = (size_t)(o0+oo)*K + k0 + k8;
      *(s8v*)&Ah[oo][k8] = *(const s8v*)(Ahg+sp);
    }
    {
      int nn = t>>2, k8 = (t&3)*8, gk = k0+k8;
      const ushort *sh, *sl;
      if (gk < ksplit){
        size_t sp = (size_t)z*sBT + (size_t)(n0+nn)*Kb + gk;
        sh = Bhg+sp; sl = Blg+sp;
      } else {
        size_t sp = (size_t)z*(K-ksplit) + (gk-ksplit);
        sh = gfh+sp; sl = gfl+sp;
      }
      *(s8v*)&Bh[nn][k8] = *(const s8v*)sh;
      *(s8v*)&Bl[nn][k8] = *(const s8v*)sl;
    }
    __syncthreads();

    s8v ah[4], bh[2], bl[2];
    #pragma unroll
    for (int mt=0;mt<4;mt++){
      int row = wm*64 + mt*16 + lr;
      ah[mt] = *(const s8v*)&Ah[row][kg*8];
    }
    #pragma unroll
    for (int nt=0;nt<2;nt++){
      int col = wn*32 + nt*16 + lr;
      bh[nt] = *(const s8v*)&Bh[col][kg*8];
      bl[nt] = *(const s8v*)&Bl[col][kg*8];
    }
    #pragma unroll
    for (int mt=0;mt<4;mt++)
      #pragma unroll
      for (int nt=0;nt<2;nt++){
        acc[mt][nt] = __builtin_amdgcn_mfma_f32_16x16x32_bf16(ah[mt], bh[nt], acc[mt][nt], 0,0,0);
        acc[mt][nt] = __builtin_amdgcn_mfma_f32_16x16x32_bf16(ah[mt], bl[nt], acc[mt][nt], 0,0,0);
      }
  }

  if (EPI == 1 || EPI == 4){
    #pragma unroll
    for (int mt=0;mt<4;mt++){
      #pragma unroll
      for (int e=0;e<4;e++){
        int row = o0 + wm*64 + mt*16 + kg*4 + e;
        float bv = bias[row];
        float v0 = fmaxf(acc[mt][0][e]+bv, 0.f);
        float v1 = fmaxf(acc[mt][1][e]+bv, 0.f);
        if (EPI == 4){
          int col0 = n0 + wn*32 + lr;
          ushort h,l;
          splitbf(v0, h, l);
          size_t p0 = ((size_t)z*N + col0)*(size_t)M + row;
          oth[p0]=h; otl[p0]=l;
          splitbf(v1, h, l);
          size_t p1 = ((size_t)z*N + col0+16)*(size_t)M + row;
          oth[p1]=h; otl[p1]=l;
        }
        float m = fmaxf(v0, v1);
        m = fmaxf(m, __shfl_xor(m, 1, 64));
        m = fmaxf(m, __shfl_xor(m, 2, 64));
        m = fmaxf(m, __shfl_xor(m, 4, 64));
        m = fmaxf(m, __shfl_xor(m, 8, 64));
        if (lr == 0) red[wn][wm*64 + mt*16 + kg*4 + e] = m;
      }
    }
    __syncthreads();
    if (t < 128){
      float m = fmaxf(red[0][t], red[1][t]);
      pmaxp[((size_t)z*M + o0 + t)*nparts + bx] = m;
    }
  } else {
    #pragma unroll
    for (int mt=0;mt<4;mt++){
      #pragma unroll
      for (int nt=0;nt<2;nt++){
        int col = n0 + wn*32 + nt*16 + lr;
        #pragma unroll
        for (int e=0;e<4;e++){
          int row = o0 + wm*64 + mt*16 + kg*4 + e;
          float bv = BCOL ? bias[col] : bias[row];
          float v = acc[mt][nt][e] + bv;
          if (RELU) v = fmaxf(v, 0.f);
          if (EPI == 0)
            outp[(size_t)z*sOut + (size_t)row*N + col] = v;
          if (EPI == 3){
            ushort h,l; splitbf(v, h, l);
            size_t p = ((size_t)z*N + col)*(size_t)M + row;
            oth[p]=h; otl[p]=l;
          }
        }
      }
    }
  }
}

template<int EPI, int RELU, int BCOL>
__global__ __launch_bounds__(256) void k_bgemm(
    const ushort* __restrict__ Ahg,
    const ushort* __restrict__ Bhg, const ushort* __restrict__ Blg,
    const ushort* __restrict__ gfh, const ushort* __restrict__ gfl,
    const float* __restrict__ bias,
    float* __restrict__ outp, float* __restrict__ pmaxp,
    ushort* __restrict__ oth, ushort* __restrict__ otl,
    int K, int ksplit, int Kb, int N, size_t sBT, size_t sOut, int M)
{
  bgemm_body<EPI,RELU,BCOL>(Ahg, Bhg, Blg, gfh, gfl, bias, outp, pmaxp, oth, otl,
                            K, ksplit, Kb, N, sBT, sOut, M,
                            blockIdx.x, blockIdx.y, blockIdx.z, gridDim.x);
}

__global__ void k_xmax(const float* __restrict__ pmax, float* __restrict__ xmax){
  int id = blockIdx.x*256 + threadIdx.x;
  if (id >= BB*1024) return;
  float m = pmax[(size_t)id*32];
  for (int k=1;k<32;k++) m = fmaxf(m, pmax[(size_t)id*32+k]);
  xmax[id] = m;
}

/* ---------------- JAX threefry PRNG ---------------- */

#define TF2BODY \
  unsigned ks2 = 0x1BD11BDAu ^ k0 ^ k1; \
  unsigned a = x0 + k0, b = x1 + k1; \
  { \
  a += b; b = (b<<13)|(b>>19); b ^= a; \
  a += b; b = (b<<15)|(b>>17); b ^= a; \
  a += b; b = (b<<26)|(b>>6);  b ^= a; \
  a += b; b = (b<<6) |(b>>26); b ^= a;  a += k1;  b += ks2 + 1u; \
  a += b; b = (b<<17)|(b>>15); b ^= a; \
  a += b; b = (b<<29)|(b>>3);  b ^= a; \
  a += b; b = (b<<16)|(b>>16); b ^= a; \
  a += b; b = (b<<24)|(b>>8);  b ^= a;  a += ks2; b += k0  + 2u; \
  a += b; b = (b<<13)|(b>>19); b ^= a; \
  a += b; b = (b<<15)|(b>>17); b ^= a; \
  a += b; b = (b<<26)|(b>>6);  b ^= a; \
  a += b; b = (b<<6) |(b>>26); b ^= a;  a += k0;  b += k1  + 3u; \
  a += b; b = (b<<17)|(b>>15); b ^= a; \
  a += b; b = (b<<29)|(b>>3);  b ^= a; \
  a += b; b = (b<<16)|(b>>16); b ^= a; \
  a += b; b = (b<<24)|(b>>8);  b ^= a;  a += k1;  b += ks2 + 4u; \
  a += b; b = (b<<13)|(b>>19); b ^= a; \
  a += b; b = (b<<15)|(b>>17); b ^= a; \
  a += b; b = (b<<26)|(b>>6);  b ^= a; \
  a += b; b = (b<<6) |(b>>26); b ^= a;  a += ks2; b += k0  + 5u; \
  } \
  o0 = a; o1 = b;

__device__ __forceinline__ void tf2(unsigned k0, unsigned k1, unsigned x0, unsigned x1,
                                    unsigned &o0, unsigned &o1){ TF2BODY }
static void tf2h(unsigned k0, unsigned k1, unsigned x0, unsigned x1,
                 unsigned &o0, unsigned &o1){ TF2BODY }

__global__ void k_permkeys3(unsigned a0, unsigned a1, unsigned* __restrict__ ka,
                            unsigned b0, unsigned b1, unsigned* __restrict__ kb,
                            unsigned c0, unsigned c1, unsigned* __restrict__ kc){
  int id = blockIdx.x*256 + threadIdx.x;
  if (id < 2048){ unsigned x,y; tf2(a0,a1, 0u,(unsigned)id, x,y); ka[id] = x^y; }
  if (id < 2048){ unsigned x,y; tf2(b0,b1, 0u,(unsigned)id, x,y); kb[id] = x^y; }
  if (id < 512){ unsigned x,y; tf2(c0,c1, 0u,(unsigned)id, x,y); kc[id] = x^y; }
}

/* ---------------- KNN body ---------------- */

template<int CPL, int KSEL>
__device__ __forceinline__ void knn_body(const float* __restrict__ vbcs,
                                         int numQ, int* __restrict__ out,
                                         int bx, int by){
  constexpr int V = CPL*64;
  constexpr int GS = (CPL < 8) ? CPL : 8;
  constexpr int NG = CPL/GS;
  int t = threadIdx.x, wid = t>>6, lane = t&63;
  int b = by;
  int q = bx*4 + wid;
  if (q >= numQ) return;
  const float* vx = vbcs + (size_t)b*3*V;
  const float* vy = vx + V;
  const float* vz = vy + V;
  float qx = vx[q], qy = vy[q], qz = vz[q];
  float qq = qx*qx + qy*qy + qz*qz;
  unsigned d[CPL];
  #pragma unroll
  for (int i=0;i<CPL;i++){
    int c = lane + i*64;
    float wx=vx[c], wy=vy[c], wz=vz[c];
    float inner = qx*wx + qy*wy + qz*wz;
    float ww = wx*wx + wy*wy + wz*wz;
    float dd = qq - 2.f*inner + ww;
    unsigned db = __float_as_uint(dd);
    d[i] = (db & 0x80000000u) ? ~db : (db | 0x80000000u);
  }
  unsigned long long g[NG];
  #pragma unroll
  for (int gg=0; gg<NG; gg++){
    unsigned long long m = ~0ull;
    #pragma unroll
    for (int j=0;j<GS;j++){
      int p = gg*GS+j;
      unsigned long long kk = ((unsigned long long)d[p]<<32) | (unsigned)p;
      m = (kk<m)?kk:m;
    }
    g[gg] = m;
  }
  unsigned lmin = (unsigned)(g[0]>>32);
  #pragma unroll
  for (int gg=1;gg<NG;gg++){ unsigned x = (unsigned)(g[gg]>>32); lmin = (x<lmin)?x:lmin; }

  int* orow = out + ((size_t)b*numQ + q)*KSEL;
  for (int r=0; r<=KSEL; r++){
    unsigned bd = lmin;
    #pragma unroll
    for (int off=32; off>0; off>>=1){
      unsigned o = __shfl_xor(bd, off, 64);
      bd = (o < bd) ? o : bd;
    }
    unsigned long long bal = __ballot(lmin == bd);
    int winner = __ffsll(bal) - 1;
    if (lane == winner){
      unsigned long long mbest = g[0];
      #pragma unroll
      for (int gg=1;gg<NG;gg++) mbest = (g[gg]<mbest)?g[gg]:mbest;
      int pos = (int)(mbest & 0xffffffffull);
      if (r>0) orow[r-1] = lane + pos*64;
      int gi = pos / GS;
      #pragma unroll
      for (int gg=0; gg<NG; gg++){
        if (gg == gi){
          unsigned long long m = ~0ull;
          #pragma unroll
          for (int j=0;j<GS;j++){
            int p = gg*GS+j;
            unsigned long long kk = ((unsigned long long)d[p]<<32) | (unsigned)p;
            if (kk <= mbest) kk = ~0ull;
            m = (kk<m)?kk:m;
          }
          g[gg] = m;
        }
      }
      unsigned nl = (unsigned)(g[0]>>32);
      #pragma unroll
      for (int gg=1;gg<NG;gg++){ unsigned x = (unsigned)(g[gg]>>32); nl = (x<nl)?x:nl; }
      lmin = nl;
    }
  }
}

template<int CPL, int KSEL>
__global__ __launch_bounds__(256,4) void k_knn_s(const float* __restrict__ vbcs,
                                                 int numQ, int* __restrict__ out){
  knn_body<CPL,KSEL>(vbcs, numQ, out, blockIdx.x, blockIdx.y);
}

/* ---------------- FUSED: knn<32,20> || mlp4max bgemm || perm ranks ----------------
   Independent work merged into one launch for single-stream concurrency.
   grid (769, 16): bx<512 knn; bx in [512,768) bgemm (nx/oy from bx-512, z=by);
   bx==768: by==0 -> 2-round 2048 rank chain, by==1 -> 512 rank. */
__global__ __launch_bounds__(256,4) void k_fused(
    const float* __restrict__ vbcs, int numQ, int* __restrict__ outIdx,
    const ushort* __restrict__ Ahg, const ushort* __restrict__ Bhg, const ushort* __restrict__ Blg,
    const float* __restrict__ bias, float* __restrict__ pmaxp,
    const unsigned* __restrict__ pk1, const unsigned* __restrict__ pk2,
    const unsigned* __restrict__ pk3,
    int* __restrict__ p2048, int* __restrict__ p512)
{
  int bx = blockIdx.x, by = blockIdx.y;
  if (bx < 512){
    knn_body<32,20>(vbcs, numQ, outIdx, bx, by);
  } else if (bx < 768){
    int loc = bx - 512;               // [0,256): 32 n-tiles x 8 o-tiles
    int nx = loc & 31, oy = loc >> 5; // z = by
    bgemm_body<1,1,0>(Ahg, Bhg, Blg, nullptr, nullptr, bias,
                      nullptr, pmaxp, nullptr, nullptr,
                      256, 256, 256, 2048, (size_t)2048*256, 0, 1024,
                      nx, oy, by, 32);
  } else {
    __shared__ unsigned kbuf[2048];
    __shared__ int va[2048];
    int t = threadIdx.x;
    if (by == 0){
      for (int i=t;i<2048;i+=256) kbuf[i]=pk1[i];
      __syncthreads();
      unsigned ki[8]; int rv[8]; int ith[8];
      #pragma unroll
      for (int c=0;c<8;c++){ ith[c]=t+c*256; ki[c]=kbuf[ith[c]]; rv[c]=0; }
      for (int j=0;j<2048;j++){
        unsigned kj = kbuf[j];
        #pragma unroll
        for (int c=0;c<8;c++)
          rv[c] += ((kj<ki[c]) || (kj==ki[c] && j<ith[c])) ? 1 : 0;
      }
      __syncthreads();
      #pragma unroll
      for (int c=0;c<8;c++) va[rv[c]] = ith[c];
      __syncthreads();
      for (int i=t;i<2048;i+=256) kbuf[i]=pk2[i];
      __syncthreads();
      #pragma unroll
      for (int c=0;c<8;c++){ ki[c]=kbuf[ith[c]]; rv[c]=0; }
      for (int j=0;j<2048;j++){
        unsigned kj = kbuf[j];
        #pragma unroll
        for (int c=0;c<8;c++)
          rv[c] += ((kj<ki[c]) || (kj==ki[c] && j<ith[c])) ? 1 : 0;
      }
      #pragma unroll
      for (int c=0;c<8;c++) p2048[rv[c]] = va[ith[c]];
    } else if (by == 1){
      for (int i=t;i<512;i+=256) kbuf[i]=pk3[i];
      __syncthreads();
      #pragma unroll
      for (int c=0;c<2;c++){
        int i = t + c*256;
        unsigned ki = kbuf[i];
        int r=0;
        for (int j=0;j<512;j++){ unsigned kj=kbuf[j]; r += (kj<ki)||(kj==ki && j<i); }
        p512[r]=i;
      }
    }
  }
}

/* ---------------- graph branch helpers ---------------- */

__global__ void k_dirs_soa(const float* __restrict__ vbcs, int V,
                           const int* __restrict__ idx, float* __restrict__ dirs,
                           int total){
  int id = blockIdx.x*256 + threadIdx.x;
  if (id >= total) return;
  int v = (id/20) % V, b = id/(20*V);
  const float* vx = vbcs + (size_t)b*3*V;
  const float* vy = vx + V;
  const float* vz = vy + V;
  int nb = idx[id];
  float dx = vx[nb]-vx[v];
  float dy = vy[nb]-vy[v];
  float dz = vz[nb]-vz[v];
  float s = 1.f / fmaxf(sqrtf(dx*dx+dy*dy+dz*dz), 1e-12f);
  dirs[(size_t)id*3+0]=dx*s; dirs[(size_t)id*3+1]=dy*s; dirs[(size_t)id*3+2]=dz*s;
}

__global__ void k_surf4(const float* __restrict__ dirs, const float* __restrict__ dir0,
                        ushort* __restrict__ fh, int V){
  int id = blockIdx.x*256 + threadIdx.x;
  if (id >= BB*V*8) return;
  int k4 = (id & 7)*4; int vv = (id>>3) % V; int b = id/(8*V);
  f4v nx = *(const f4v*)&dir0[k4];
  f4v ny = *(const f4v*)&dir0[32+k4];
  f4v nz = *(const f4v*)&dir0[64+k4];
  #pragma unroll
  for (int j=0;j<4;j++){
    float s = 1.f/fmaxf(sqrtf(nx[j]*nx[j]+ny[j]*ny[j]+nz[j]*nz[j]), 1e-12f);
    nx[j]*=s; ny[j]*=s; nz[j]*=s;
  }
  const float* dd = dirs + (size_t)(b*V+vv)*60;
  f4v m = (f4v){0.f,0.f,0.f,0.f};
  for (int n=0;n<20;n++){
    float d0=dd[n*3], d1=dd[n*3+1], d2=dd[n*3+2];
    #pragma unroll
    for (int j=0;j<4;j++){
      float th = d0*nx[j] + d1*ny[j] + d2*nz[j];
      m[j] = fmaxf(m[j], fmaxf(th, 0.f));
    }
  }
  size_t p = (size_t)(b*V+vv)*32 + k4;
  #pragma unroll
  for (int j=0;j<4;j++) fh[p+j] = f2bf(m[j]);
}

template<int OUT>
__global__ void k_comb4(const float* __restrict__ feat, const int* __restrict__ idx,
                        const float* __restrict__ dirs, const float* __restrict__ dw,
                        float* __restrict__ outp, ushort* __restrict__ oh,
                        int V, int OC, int relu_flag){
  int id = blockIdx.x*256 + threadIdx.x;
  int OC4 = OC>>2;
  if (id >= BB*V*OC4) return;
  int o4 = (id % OC4)*4, v = (id/OC4) % V, b = id/(OC4*V);
  f4v wx = *(const f4v*)&dw[o4];
  f4v wy = *(const f4v*)&dw[OC+o4];
  f4v wz = *(const f4v*)&dw[2*OC+o4];
  #pragma unroll
  for (int j=0;j<4;j++){
    float s = 1.f/fmaxf(sqrtf(wx[j]*wx[j]+wy[j]*wy[j]+wz[j]*wz[j]), 1e-12f);
    wx[j]*=s; wy[j]*=s; wz[j]*=s;
  }
  size_t row = (size_t)b*V + v;
  const int* ir = idx + row*20;
  const float* dd = dirs + row*60;
  f4v center = *(const f4v*)&feat[row*2*OC + o4];
  f4v m = (f4v){-INFINITY,-INFINITY,-INFINITY,-INFINITY};
  for (int n=0;n<20;n++){
    int nb = ir[n];
    float d0=dd[n*3], d1=dd[n*3+1], d2=dd[n*3+2];
    f4v sup = *(const f4v*)&feat[((size_t)b*V + nb)*2*OC + OC + o4];
    #pragma unroll
    for (int j=0;j<4;j++){
      float th = fmaxf(d0*wx[j] + d1*wy[j] + d2*wz[j], 0.f);
      m[j] = fmaxf(m[j], th*sup[j]);
    }
  }
  if (OUT == 0){
    f4v rv;
    #pragma unroll
    for (int j=0;j<4;j++){
      float x = center[j] + m[j];
      rv[j] = relu_flag ? fmaxf(x, 0.f) : x;
    }
    *(f4v*)&outp[row*OC + o4] = rv;
  } else {
    #pragma unroll
    for (int j=0;j<4;j++)
      oh[row*OC + o4 + j] = f2bf(fmaxf(center[j] + m[j], 0.f));
  }
}

template<int OUT>
__global__ void k_pool(const float* __restrict__ fm, const int* __restrict__ idxsrc,
                       const int* __restrict__ perm,
                       float* __restrict__ outp, ushort* __restrict__ oh,
                       int V, int C, int numS){
  int id = blockIdx.x*256 + threadIdx.x;
  if (id >= BB*numS*C) return;
  int c = id % C, sI = (id/C) % numS, b = id/(C*numS);
  const int* ir = idxsrc + ((size_t)b*V + perm[sI])*20;
  float m = -INFINITY;
  for (int n=0;n<4;n++) m = fmaxf(m, fm[((size_t)b*V + ir[n])*C + c]);
  size_t p = ((size_t)b*numS + sI)*C + c;
  if (OUT == 0) outp[p] = m;
  else oh[p] = f2bf(m);
}

__global__ void k_vgather(const float* __restrict__ vsrc, const int* __restrict__ perm,
                          float* __restrict__ vbcs, int V, int numS){
  int id = blockIdx.x*256 + threadIdx.x;
  if (id >= BB*3*numS) return;
  int s = id % numS, c = (id/numS) % 3, b = id/(3*numS);
  vbcs[id] = vsrc[((size_t)b*3 + c)*V + perm[s]];
}

__global__ void k_colmax(const float* __restrict__ x, float* __restrict__ o, int Vr, int C){
  int id = blockIdx.x*256 + threadIdx.x;
  if (id >= BB*C) return;
  int c = id % C, b = id / C;
  float m = -INFINITY;
  for (int v=0; v<Vr; v++) m = fmaxf(m, x[(size_t)(b*Vr+v)*C + c]);
  o[id] = m;
}

/* ---------------- FC head ---------------- */

// fused embedding + h (independent wave-per-output dot products)
__global__ __launch_bounds__(256) void k_embh(const float* __restrict__ xmax, const float* __restrict__ fg,
                                              const float* __restrict__ fcw, const float* __restrict__ fcb,
                                              const float* __restrict__ clw1, const float* __restrict__ clb1,
                                              const float* __restrict__ gamma, const float* __restrict__ beta,
                                              float* __restrict__ outp, float* __restrict__ h){
  int gid = blockIdx.x*4 + (threadIdx.x>>6);
  int lane = threadIdx.x & 63;
  if (gid >= 2*BB*512) return;
  bool isH = gid >= BB*512;
  int g2 = isH ? gid - BB*512 : gid;
  int e = g2 & 511, b = g2 >> 9;
  const float* wr = (isH ? clw1 : fcw) + (size_t)e*2048;
  const float* xb = xmax + b*1024;
  const float* gb = fg + b*1024;
  float acc = 0.f;
  for (int k=lane; k<1024; k+=64)
    acc += xb[k]*wr[k] + gb[k]*wr[1024+k];
  #pragma unroll
  for (int off=32; off>0; off>>=1) acc += __shfl_xor(acc, off, 64);
  if (lane==0){
    if (isH){
      const float inv_s = 1.0f / sqrtf(1.0f + 1e-5f);
      float v = (acc + clb1[e]) * inv_s * gamma[e] + beta[e];
      h[g2] = fmaxf(v, 0.f);
    } else {
      outp[g2] = acc + fcb[e];
    }
  }
}

__global__ __launch_bounds__(256) void k_pred2(const float* __restrict__ h, const float* __restrict__ clw2,
                                               const float* __restrict__ clb2, float* __restrict__ outp){
  int gid = blockIdx.x*4 + (threadIdx.x>>6);
  int lane = threadIdx.x & 63;
  if (gid >= BB*6) return;
  int o = gid % 6, b = gid / 6;
  const float* hb = h + b*512;
  const float* wr = clw2 + o*512;
  float acc = 0.f;
  for (int k=lane; k<512; k+=64) acc += hb[k]*wr[k];
  #pragma unroll
  for (int off=32; off>0; off>>=1) acc += __shfl_xor(acc, off, 64);
  if (lane==0) outp[BB*512 + gid] = acc + clb2[o];
}

/* ---------------- launch ---------------- */

static inline int cdiv(long long a, int b){ return (int)((a + b - 1)/b); }

extern "C" void kernel_launch(void* const* d_in, const int* in_sizes, int n_in,
                              void* d_out, int out_size, void* d_ws, size_t ws_size,
                              hipStream_t stream){
  float* out = (float*)d_out;
  if (n_in != 30 || in_sizes[0] != BB*3*NN || out_size != BB*512 + BB*6){
    k_sentinel<<<cdiv(out_size,256),256,0,stream>>>(out, out_size, 2000.0f);
    return;
  }
  const float* xyz  = (const float*)d_in[0];
  const float* w1   = (const float*)d_in[1];
  const float* b1   = (const float*)d_in[2];
  const float* w2   = (const float*)d_in[3];
  const float* b2   = (const float*)d_in[4];
  const float* w3   = (const float*)d_in[5];
  const float* b3   = (const float*)d_in[6];
  const float* w4   = (const float*)d_in[7];
  const float* b4   = (const float*)d_in[8];
  const float* fcw  = (const float*)d_in[9];
  const float* fcb  = (const float*)d_in[10];
  const float* dir0 = (const float*)d_in[11];
  const float* wc1  = (const float*)d_in[12];
  const float* bc1  = (const float*)d_in[13];
  const float* dir1 = (const float*)d_in[14];
  const float* wc2  = (const float*)d_in[15];
  const float* bc2  = (const float*)d_in[16];
  const float* dir2 = (const float*)d_in[17];
  const float* wc3  = (const float*)d_in[18];
  const float* bc3  = (const float*)d_in[19];
  const float* dir3 = (const float*)d_in[20];
  const float* wc4  = (const float*)d_in[21];
  const float* bc4  = (const float*)d_in[22];
  const float* dir4 = (const float*)d_in[23];
  const float* clw1 = (const float*)d_in[24];
  const float* clb1 = (const float*)d_in[25];
  const float* gma  = (const float*)d_in[26];
  const float* bta  = (const float*)d_in[27];
  const float* clw2 = (const float*)d_in[28];
  const float* clb2 = (const float*)d_in[29];

  char* w = (char*)d_ws;
  size_t off = 0;
  auto A = [&](size_t bytes){ size_t r = off; off += (bytes + 255) & ~(size_t)255; return r; };
  const size_t oXMAX = A((size_t)BB*1024*4);
  const size_t oFG   = A((size_t)BB*1024*4);
  const size_t oGFP  = A((size_t)BB*128*2*2);
  const size_t oH    = A((size_t)BB*512*4);
  const size_t oP2048= A(2048*4);
  const size_t oP512 = A(512*4);
  const size_t oPK1  = A(2048*4);
  const size_t oPK2  = A(2048*4);
  const size_t oPK3  = A(512*4);
  const size_t oPMAX = A((size_t)BB*1024*32*4);
  const size_t oV1S  = A((size_t)BB*3*512*4);
  const size_t oV2S  = A((size_t)BB*3*128*4);
  const size_t oIDX0 = A((size_t)BB*2048*20*4);   // aliased by x2T planes (dead before fused)
  const size_t oDIR0 = A((size_t)BB*2048*20*3*4);
  const size_t oFM0  = A((size_t)BB*2048*32*2);
  const size_t oFM1  = A((size_t)BB*2048*64*4);
  const size_t oFM1P = A((size_t)BB*512*64*2);
  const size_t oIDX1 = A((size_t)BB*512*20*4);
  const size_t oDIR1 = A((size_t)BB*512*20*3*4);
  const size_t oFM2  = A((size_t)BB*512*128*2);
  const size_t oFM3  = A((size_t)BB*512*256*4);
  const size_t oFM3P = A((size_t)BB*128*256*2);
  const size_t oIDX2 = A((size_t)BB*128*20*4);
  const size_t oDIR2 = A((size_t)BB*128*20*3*4);
  const size_t oFM4  = A((size_t)BB*128*1024*4);
  const size_t oBIGA = A((size_t)BB*256*NN*4);    // x1T planes then x3T planes
  const size_t oBIGB = A((size_t)BB*128*NN*4);    // feat f32
  const size_t oW2P  = A((size_t)128*64*2);
  const size_t oW3P  = A((size_t)256*256*2);
  const size_t oW4P  = A((size_t)1024*256*2);
  const size_t oWC1T = A((size_t)32*128*2*2);
  const size_t oWC2T = A((size_t)64*256*2*2);
  const size_t oWC3T = A((size_t)128*512*2*2);
  const size_t oWC4T = A((size_t)256*2048*2*2);
  if (off > ws_size){
    k_sentinel<<<cdiv(out_size,256),256,0,stream>>>(out, out_size, 1000.0f);
    return;
  }
  float* xmax = (float*)(w+oXMAX); float* fg = (float*)(w+oFG);
  float* hbuf = (float*)(w+oH);
  ushort* gfh = (ushort*)(w+oGFP); ushort* gfl = gfh + BB*128;
  int* p2048 = (int*)(w+oP2048);   int* p512 = (int*)(w+oP512);
  unsigned* pk1 = (unsigned*)(w+oPK1); unsigned* pk2 = (unsigned*)(w+oPK2);
  unsigned* pk3 = (unsigned*)(w+oPK3);
  float* pmax = (float*)(w+oPMAX);
  float* v1s = (float*)(w+oV1S); float* v2s = (float*)(w+oV2S);
  int* idx0 = (int*)(w+oIDX0); int* idx1 = (int*)(w+oIDX1); int* idx2 = (int*)(w+oIDX2);
  float* d0 = (float*)(w+oDIR0); float* d1 = (float*)(w+oDIR1); float* d2 = (float*)(w+oDIR2);
  ushort* fm0h = (ushort*)(w+oFM0);
  float* fm1 = (float*)(w+oFM1);
  ushort* fm1ph = (ushort*)(w+oFM1P);
  ushort* fm2h = (ushort*)(w+oFM2);
  float* fm3 = (float*)(w+oFM3);
  ushort* fm3ph = (ushort*)(w+oFM3P);
  float* fm4 = (float*)(w+oFM4);
  ushort* x1h = (ushort*)(w+oBIGA); ushort* x1l = x1h + (size_t)BB*2048*64;
  ushort* x3h = (ushort*)(w+oBIGA); ushort* x3l = x3h + (size_t)BB*2048*256;
  ushort* x2h = (ushort*)(w+oIDX0); ushort* x2l = x2h + (size_t)BB*2048*128;
  float* feat = (float*)(w+oBIGB);
  ushort* w2ph = (ushort*)(w+oW2P);
  ushort* w3ph = (ushort*)(w+oW3P);
  ushort* w4ph = (ushort*)(w+oW4P);
  ushort* wc1h = (ushort*)(w+oWC1T); ushort* wc1l = wc1h + 32*128;
  ushort* wc2h = (ushort*)(w+oWC2T); ushort* wc2l = wc2h + 64*256;
  ushort* wc3h = (ushort*)(w+oWC3T); ushort* wc3l = wc3h + 128*512;
  ushort* wc4h = (ushort*)(w+oWC4T); ushort* wc4l = wc4h + 256*2048;

  // weight pre-split
  k_wsplit3h<<<cdiv(128*64+256*256+1024*256,256),256,0,stream>>>(
      w2, w2ph, 128*64,  w3, w3ph, 256*256,  w4, w4ph, 1024*256);
  k_wstr4<<<cdiv(32*128+64*256+128*512+256*2048,256),256,0,stream>>>(
      wc1, wc1h, wc1l, 32, 128,  wc2, wc2h, wc2l, 64, 256,
      wc3, wc3h, wc3l, 128, 512, wc4, wc4h, wc4l, 256, 2048);

  // MLP chain up to x3 (so mlp4max is ready for the fused launch)
  k_mlp1s<<<cdiv((long long)BB*NN*64,256),256,0,stream>>>(xyz, w1, b1, x1h, x1l);
  k_bgemm<4,1,0><<<dim3(32,1,BB),256,0,stream>>>(w2ph, x1h, x1l, nullptr, nullptr,
      b2, nullptr, pmax, x2h, x2l, 64, 64, 64, 2048, (size_t)2048*64, 0, 128);
  k_gmax<<<cdiv(BB*128,256),256,0,stream>>>(pmax, gfh, gfl, 32, BB*128);
  k_bgemm<3,1,0><<<dim3(32,2,BB),256,0,stream>>>(w3ph, x2h, x2l, gfh, gfl,
      b3, nullptr, nullptr, x3h, x3l, 256, 128, 128, 2048, (size_t)2048*128, 0, 256);

  // permutation keys (ranks happen inside the fused launch)
  {
    unsigned ck0=0u, ck1=1u, nk0,nk1, s00,s01, s10,s11, sc0,sc1;
    tf2h(ck0,ck1, 0u,0u, nk0,nk1);
    tf2h(ck0,ck1, 0u,1u, s00,s01);
    tf2h(nk0,nk1, 0u,1u, s10,s11);
    tf2h(0u,2u,  0u,1u, sc0,sc1);
    k_permkeys3<<<8,256,0,stream>>>(s00,s01,pk1, s10,s11,pk2, sc0,sc1,pk3);
  }

  // FUSED: big KNN || mlp4max || perm ranks
  k_fused<<<dim3(769,16),256,0,stream>>>(xyz, 2048, idx0,
      w4ph, x3h, x3l, b4, pmax, pk1, pk2, pk3, p2048, p512);
  k_xmax<<<cdiv(BB*1024,256),256,0,stream>>>(pmax, xmax);

  // graph branch: stage 0 (V=2048)
  k_dirs_soa<<<cdiv((long long)BB*2048*20,256),256,0,stream>>>(xyz, 2048, idx0, d0, BB*2048*20);
  k_surf4<<<cdiv((long long)BB*2048*8,256),256,0,stream>>>(d0, dir0, fm0h, 2048);
  k_bgemm<0,0,1><<<dim3(2,256,1),256,0,stream>>>(fm0h, wc1h, wc1l, nullptr, nullptr,
      bc1, feat, nullptr, nullptr, nullptr, 32, 32, 32, 128, 0, 0, BB*2048);
  k_comb4<0><<<cdiv((long long)BB*2048*16,256),256,0,stream>>>(feat, idx0, d0, dir1, fm1, nullptr, 2048, 64, 1);
  // pool 1
  k_pool<1><<<cdiv((long long)BB*512*64,256),256,0,stream>>>(fm1, idx0, p2048, nullptr, fm1ph, 2048, 64, 512);
  k_vgather<<<cdiv((long long)BB*3*512,256),256,0,stream>>>(xyz, p2048, v1s, 2048, 512);
  // stage 1 (V=512)
  k_knn_s<8,20><<<dim3(128,BB),256,0,stream>>>(v1s, 512, idx1);
  k_dirs_soa<<<cdiv((long long)BB*512*20,256),256,0,stream>>>(v1s, 512, idx1, d1, BB*512*20);
  k_bgemm<0,0,1><<<dim3(4,64,1),256,0,stream>>>(fm1ph, wc2h, wc2l, nullptr, nullptr,
      bc2, feat, nullptr, nullptr, nullptr, 64, 64, 64, 256, 0, 0, BB*512);
  k_comb4<1><<<cdiv((long long)BB*512*32,256),256,0,stream>>>(feat, idx1, d1, dir2, nullptr, fm2h, 512, 128, 1);
  k_bgemm<0,0,1><<<dim3(8,64,1),256,0,stream>>>(fm2h, wc3h, wc3l, nullptr, nullptr,
      bc3, feat, nullptr, nullptr, nullptr, 128, 128, 128, 512, 0, 0, BB*512);
  k_comb4<0><<<cdiv((long long)BB*512*64,256),256,0,stream>>>(feat, idx1, d1, dir3, fm3, nullptr, 512, 256, 1);
  // pool 2
  k_pool<1><<<cdiv((long long)BB*128*256,256),256,0,stream>>>(fm3, idx1, p512, nullptr, fm3ph, 512, 256, 128);
  k_vgather<<<cdiv((long long)BB*3*128,256),256,0,stream>>>(v1s, p512, v2s, 512, 128);
  // stage 2 (V=128)
  k_knn_s<2,20><<<dim3(32,BB),256,0,stream>>>(v2s, 128, idx2);
  k_dirs_soa<<<cdiv((long long)BB*128*20,256),256,0,stream>>>(v2s, 128, idx2, d2, BB*128*20);
  k_bgemm<0,0,1><<<dim3(32,16,1),256,0,stream>>>(fm3ph, wc4h, wc4l, nullptr, nullptr,
      bc4, feat, nullptr, nullptr, nullptr, 256, 256, 256, 2048, 0, 0, BB*128);
  k_comb4<0><<<cdiv((long long)BB*128*256,256),256,0,stream>>>(feat, idx2, d2, dir4, fm4, nullptr, 128, 1024, 0);
  k_colmax<<<cdiv(BB*1024,256),256,0,stream>>>(fm4, fg, 128, 1024);

  // FC head
  k_embh<<<cdiv(2*BB*512,4),256,0,stream>>>(xmax, fg, fcw, fcb, clw1, clb1, gma, bta, out, hbuf);
  k_pred2<<<cdiv(BB*6,4),256,0,stream>>>(hbuf, clw2, clb2, out);
}

// Round 14
// 645.094 us; speedup vs baseline: 1.4020x; 1.4020x over previous
//
#include <hip/hip_runtime.h>
#include <hip/hip_bf16.h>
#include <math.h>

#define BB 16
#define NN 2048

typedef __attribute__((ext_vector_type(8))) short s8v;
typedef __attribute__((ext_vector_type(4))) float f4v;

__global__ void k_sentinel(float* o, int n, float v){
  int i = blockIdx.x*256 + threadIdx.x;
  if (i < n) o[i] = v;
}

__device__ __forceinline__ ushort f2bf(float x){
  unsigned u = __float_as_uint(x);
  unsigned r = u + 0x7FFFu + ((u>>16)&1u);
  return (ushort)(r>>16);
}
__device__ __forceinline__ void splitbf(float v, ushort &h, ushort &l){
  h = f2bf(v);
  float hf = __uint_as_float((unsigned)h<<16);
  l = f2bf(v-hf);
}

/* ---------------- weight pre-split ---------------- */

__global__ void k_wsplit3h(const float* __restrict__ s1, ushort* __restrict__ d1h, int n1,
                           const float* __restrict__ s2, ushort* __restrict__ d2h, int n2,
                           const float* __restrict__ s3, ushort* __restrict__ d3h, int n3){
  int id = blockIdx.x*256 + threadIdx.x;
  const float* s; ushort *dh; int i;
  if (id < n1){ s=s1; dh=d1h; i=id; }
  else if (id < n1+n2){ s=s2; dh=d2h; i=id-n1; }
  else if (id < n1+n2+n3){ s=s3; dh=d3h; i=id-n1-n2; }
  else return;
  dh[i] = f2bf(s[i]);
}

__global__ void k_wstr4(const float* __restrict__ s1, ushort* __restrict__ d1h, ushort* __restrict__ d1l, int K1, int C1,
                        const float* __restrict__ s2, ushort* __restrict__ d2h, ushort* __restrict__ d2l, int K2, int C2,
                        const float* __restrict__ s3, ushort* __restrict__ d3h, ushort* __restrict__ d3l, int K3, int C3,
                        const float* __restrict__ s4, ushort* __restrict__ d4h, ushort* __restrict__ d4l, int K4, int C4){
  int id = blockIdx.x*256 + threadIdx.x;
  int n1=K1*C1, n2=K2*C2, n3=K3*C3, n4=K4*C4;
  const float* s; ushort *dh, *dl; int i, K, C;
  if (id < n1){ s=s1; dh=d1h; dl=d1l; i=id; K=K1; C=C1; }
  else if (id < n1+n2){ s=s2; dh=d2h; dl=d2l; i=id-n1; K=K2; C=C2; }
  else if (id < n1+n2+n3){ s=s3; dh=d3h; dl=d3l; i=id-n1-n2; K=K3; C=C3; }
  else if (id < n1+n2+n3+n4){ s=s4; dh=d4h; dl=d4l; i=id-n1-n2-n3; K=K4; C=C4; }
  else return;
  int c = i % C, k = i / C;
  ushort h,l; splitbf(s[i], h, l);
  dh[(size_t)c*K + k]=h; dl[(size_t)c*K + k]=l;
}

/* ---------------- MLP branch ---------------- */

__global__ void k_mlp1s(const float* __restrict__ xyz, const float* __restrict__ w1,
                        const float* __restrict__ b1, ushort* __restrict__ xh,
                        ushort* __restrict__ xl){
  int id = blockIdx.x*256 + threadIdx.x;
  if (id >= BB*NN*64) return;
  int o = id & 63, n = (id>>6) & (NN-1), b = id>>17;
  float acc = b1[o];
  #pragma unroll
  for (int c=0;c<3;c++)
    acc += w1[o*3+c] * xyz[(size_t)(b*3+c)*NN + n];
  acc = fmaxf(acc, 0.f);
  ushort h,l; splitbf(acc, h, l);
  xh[id]=h; xl[id]=l;
}

__global__ void k_gmax(const float* __restrict__ pmax, ushort* __restrict__ gh,
                       ushort* __restrict__ gl, int parts, int total){
  int id = blockIdx.x*256 + threadIdx.x;
  if (id >= total) return;
  float m = pmax[(size_t)id*parts];
  for (int k=1;k<parts;k++) m = fmaxf(m, pmax[(size_t)id*parts+k]);
  ushort h,l; splitbf(m, h, l);
  gh[id]=h; gl[id]=l;
}

/* ---------------- 2-pass split-bf16 MFMA GEMM ----------------
   A: bf16-hi only [M][K]. B: transposed hi+lo planes [z][N][Kb];
   rows k>=ksplit read gf planes. Passes: Ah*Bh + Ah*Bl.
   EPI: 0 = f32 out; 1 = relu+colmax -> pmax; 3 = splitT planes only;
        4 = relu + splitT planes + colmax partials. */
template<int EPI, int RELU, int BCOL>
__global__ __launch_bounds__(256) void k_bgemm(
    const ushort* __restrict__ Ahg,
    const ushort* __restrict__ Bhg, const ushort* __restrict__ Blg,
    const ushort* __restrict__ gfh, const ushort* __restrict__ gfl,
    const float* __restrict__ bias,
    float* __restrict__ outp, float* __restrict__ pmaxp,
    ushort* __restrict__ oth, ushort* __restrict__ otl,
    int K, int ksplit, int Kb, int N, size_t sBT, size_t sOut, int M)
{
  __shared__ ushort Ah[128][40];
  __shared__ ushort Bh[64][40], Bl[64][40];
  __shared__ float red[2][128];
  int t = threadIdx.x, z = blockIdx.z;
  int o0 = blockIdx.y*128, n0 = blockIdx.x*64;
  int wid = t>>6, lane = t&63;
  int wm = wid>>1, wn = wid&1;
  int lr = lane&15, kg = lane>>4;

  f4v acc[4][2];
  #pragma unroll
  for (int i=0;i<4;i++)
    #pragma unroll
    for (int j=0;j<2;j++) acc[i][j] = (f4v){0.f,0.f,0.f,0.f};

  for (int k0=0; k0<K; k0+=32){
    __syncthreads();
    #pragma unroll
    for (int i=0;i<2;i++){
      int j = i*256+t, oo = j>>2, k8 = (j&3)*8;
      size_t sp = (size_t)(o0+oo)*K + k0 + k8;
      *(s8v*)&Ah[oo][k8] = *(const s8v*)(Ahg+sp);
    }
    {
      int nn = t>>2, k8 = (t&3)*8, gk = k0+k8;
      const ushort *sh, *sl;
      if (gk < ksplit){
        size_t sp = (size_t)z*sBT + (size_t)(n0+nn)*Kb + gk;
        sh = Bhg+sp; sl = Blg+sp;
      } else {
        size_t sp = (size_t)z*(K-ksplit) + (gk-ksplit);
        sh = gfh+sp; sl = gfl+sp;
      }
      *(s8v*)&Bh[nn][k8] = *(const s8v*)sh;
      *(s8v*)&Bl[nn][k8] = *(const s8v*)sl;
    }
    __syncthreads();

    s8v ah[4], bh[2], bl[2];
    #pragma unroll
    for (int mt=0;mt<4;mt++){
      int row = wm*64 + mt*16 + lr;
      ah[mt] = *(const s8v*)&Ah[row][kg*8];
    }
    #pragma unroll
    for (int nt=0;nt<2;nt++){
      int col = wn*32 + nt*16 + lr;
      bh[nt] = *(const s8v*)&Bh[col][kg*8];
      bl[nt] = *(const s8v*)&Bl[col][kg*8];
    }
    #pragma unroll
    for (int mt=0;mt<4;mt++)
      #pragma unroll
      for (int nt=0;nt<2;nt++){
        acc[mt][nt] = __builtin_amdgcn_mfma_f32_16x16x32_bf16(ah[mt], bh[nt], acc[mt][nt], 0,0,0);
        acc[mt][nt] = __builtin_amdgcn_mfma_f32_16x16x32_bf16(ah[mt], bl[nt], acc[mt][nt], 0,0,0);
      }
  }

  if (EPI == 1 || EPI == 4){
    #pragma unroll
    for (int mt=0;mt<4;mt++){
      #pragma unroll
      for (int e=0;e<4;e++){
        int row = o0 + wm*64 + mt*16 + kg*4 + e;
        float bv = bias[row];
        float v0 = fmaxf(acc[mt][0][e]+bv, 0.f);
        float v1 = fmaxf(acc[mt][1][e]+bv, 0.f);
        if (EPI == 4){
          int col0 = n0 + wn*32 + lr;
          ushort h,l;
          splitbf(v0, h, l);
          size_t p0 = ((size_t)z*N + col0)*(size_t)M + row;
          oth[p0]=h; otl[p0]=l;
          splitbf(v1, h, l);
          size_t p1 = ((size_t)z*N + col0+16)*(size_t)M + row;
          oth[p1]=h; otl[p1]=l;
        }
        float m = fmaxf(v0, v1);
        m = fmaxf(m, __shfl_xor(m, 1, 64));
        m = fmaxf(m, __shfl_xor(m, 2, 64));
        m = fmaxf(m, __shfl_xor(m, 4, 64));
        m = fmaxf(m, __shfl_xor(m, 8, 64));
        if (lr == 0) red[wn][wm*64 + mt*16 + kg*4 + e] = m;
      }
    }
    __syncthreads();
    if (t < 128){
      float m = fmaxf(red[0][t], red[1][t]);
      pmaxp[((size_t)z*M + o0 + t)*gridDim.x + blockIdx.x] = m;
    }
  } else {
    #pragma unroll
    for (int mt=0;mt<4;mt++){
      #pragma unroll
      for (int nt=0;nt<2;nt++){
        int col = n0 + wn*32 + nt*16 + lr;
        #pragma unroll
        for (int e=0;e<4;e++){
          int row = o0 + wm*64 + mt*16 + kg*4 + e;
          float bv = BCOL ? bias[col] : bias[row];
          float v = acc[mt][nt][e] + bv;
          if (RELU) v = fmaxf(v, 0.f);
          if (EPI == 0)
            outp[(size_t)z*sOut + (size_t)row*N + col] = v;
          if (EPI == 3){
            ushort h,l; splitbf(v, h, l);
            size_t p = ((size_t)z*N + col)*(size_t)M + row;
            oth[p]=h; otl[p]=l;
          }
        }
      }
    }
  }
}

__global__ void k_xmax(const float* __restrict__ pmax, float* __restrict__ xmax){
  int id = blockIdx.x*256 + threadIdx.x;
  if (id >= BB*1024) return;
  float m = pmax[(size_t)id*32];
  for (int k=1;k<32;k++) m = fmaxf(m, pmax[(size_t)id*32+k]);
  xmax[id] = m;
}

/* ---------------- JAX threefry PRNG ---------------- */

#define TF2BODY \
  unsigned ks2 = 0x1BD11BDAu ^ k0 ^ k1; \
  unsigned a = x0 + k0, b = x1 + k1; \
  { \
  a += b; b = (b<<13)|(b>>19); b ^= a; \
  a += b; b = (b<<15)|(b>>17); b ^= a; \
  a += b; b = (b<<26)|(b>>6);  b ^= a; \
  a += b; b = (b<<6) |(b>>26); b ^= a;  a += k1;  b += ks2 + 1u; \
  a += b; b = (b<<17)|(b>>15); b ^= a; \
  a += b; b = (b<<29)|(b>>3);  b ^= a; \
  a += b; b = (b<<16)|(b>>16); b ^= a; \
  a += b; b = (b<<24)|(b>>8);  b ^= a;  a += ks2; b += k0  + 2u; \
  a += b; b = (b<<13)|(b>>19); b ^= a; \
  a += b; b = (b<<15)|(b>>17); b ^= a; \
  a += b; b = (b<<26)|(b>>6);  b ^= a; \
  a += b; b = (b<<6) |(b>>26); b ^= a;  a += k0;  b += k1  + 3u; \
  a += b; b = (b<<17)|(b>>15); b ^= a; \
  a += b; b = (b<<29)|(b>>3);  b ^= a; \
  a += b; b = (b<<16)|(b>>16); b ^= a; \
  a += b; b = (b<<24)|(b>>8);  b ^= a;  a += k1;  b += ks2 + 4u; \
  a += b; b = (b<<13)|(b>>19); b ^= a; \
  a += b; b = (b<<15)|(b>>17); b ^= a; \
  a += b; b = (b<<26)|(b>>6);  b ^= a; \
  a += b; b = (b<<6) |(b>>26); b ^= a;  a += ks2; b += k0  + 5u; \
  } \
  o0 = a; o1 = b;

__device__ __forceinline__ void tf2(unsigned k0, unsigned k1, unsigned x0, unsigned x1,
                                    unsigned &o0, unsigned &o1){ TF2BODY }
static void tf2h(unsigned k0, unsigned k1, unsigned x0, unsigned x1,
                 unsigned &o0, unsigned &o1){ TF2BODY }

__global__ void k_permkeys3(unsigned a0, unsigned a1, unsigned* __restrict__ ka,
                            unsigned b0, unsigned b1, unsigned* __restrict__ kb,
                            unsigned c0, unsigned c1, unsigned* __restrict__ kc){
  int id = blockIdx.x*256 + threadIdx.x;
  if (id < 2048){ unsigned x,y; tf2(a0,a1, 0u,(unsigned)id, x,y); ka[id] = x^y; }
  if (id < 2048){ unsigned x,y; tf2(b0,b1, 0u,(unsigned)id, x,y); kb[id] = x^y; }
  if (id < 512){ unsigned x,y; tf2(c0,c1, 0u,(unsigned)id, x,y); kc[id] = x^y; }
}

__global__ void k_permrank(int n, const unsigned* __restrict__ keys,
                           const int* __restrict__ vin, int* __restrict__ vout){
  int i = blockIdx.x*256 + threadIdx.x;
  if (i >= n) return;
  unsigned ki = keys[i];
  int rank = 0;
  for (int j=0;j<n;j++){
    unsigned kj = keys[j];
    rank += (kj < ki) || (kj == ki && j < i);
  }
  vout[rank] = vin ? vin[i] : i;
}

/* ---------------- graph branch ---------------- */

// Wave-per-query KNN (round-9 form)
template<int CPL, int KSEL>
__global__ __launch_bounds__(256,4) void k_knn_s(const float* __restrict__ vbcs,
                                                 int numQ, int* __restrict__ out){
  constexpr int V = CPL*64;
  constexpr int GS = (CPL < 8) ? CPL : 8;
  constexpr int NG = CPL/GS;
  int t = threadIdx.x, wid = t>>6, lane = t&63;
  int b = blockIdx.y;
  int q = blockIdx.x*4 + wid;
  if (q >= numQ) return;
  const float* vx = vbcs + (size_t)b*3*V;
  const float* vy = vx + V;
  const float* vz = vy + V;
  float qx = vx[q], qy = vy[q], qz = vz[q];
  float qq = qx*qx + qy*qy + qz*qz;
  unsigned d[CPL];
  #pragma unroll
  for (int i=0;i<CPL;i++){
    int c = lane + i*64;
    float wx=vx[c], wy=vy[c], wz=vz[c];
    float inner = qx*wx + qy*wy + qz*wz;
    float ww = wx*wx + wy*wy + wz*wz;
    float dd = qq - 2.f*inner + ww;
    unsigned db = __float_as_uint(dd);
    d[i] = (db & 0x80000000u) ? ~db : (db | 0x80000000u);
  }
  unsigned long long g[NG];
  #pragma unroll
  for (int gg=0; gg<NG; gg++){
    unsigned long long m = ~0ull;
    #pragma unroll
    for (int j=0;j<GS;j++){
      int p = gg*GS+j;
      unsigned long long kk = ((unsigned long long)d[p]<<32) | (unsigned)p;
      m = (kk<m)?kk:m;
    }
    g[gg] = m;
  }
  unsigned lmin = (unsigned)(g[0]>>32);
  #pragma unroll
  for (int gg=1;gg<NG;gg++){ unsigned x = (unsigned)(g[gg]>>32); lmin = (x<lmin)?x:lmin; }

  int* orow = out + ((size_t)b*numQ + q)*KSEL;
  for (int r=0; r<=KSEL; r++){
    unsigned bd = lmin;
    #pragma unroll
    for (int off=32; off>0; off>>=1){
      unsigned o = __shfl_xor(bd, off, 64);
      bd = (o < bd) ? o : bd;
    }
    unsigned long long bal = __ballot(lmin == bd);
    int winner = __ffsll(bal) - 1;
    if (lane == winner){
      unsigned long long mbest = g[0];
      #pragma unroll
      for (int gg=1;gg<NG;gg++) mbest = (g[gg]<mbest)?g[gg]:mbest;
      int pos = (int)(mbest & 0xffffffffull);
      if (r>0) orow[r-1] = lane + pos*64;
      int gi = pos / GS;
      #pragma unroll
      for (int gg=0; gg<NG; gg++){
        if (gg == gi){
          unsigned long long m = ~0ull;
          #pragma unroll
          for (int j=0;j<GS;j++){
            int p = gg*GS+j;
            unsigned long long kk = ((unsigned long long)d[p]<<32) | (unsigned)p;
            if (kk <= mbest) kk = ~0ull;
            m = (kk<m)?kk:m;
          }
          g[gg] = m;
        }
      }
      unsigned nl = (unsigned)(g[0]>>32);
      #pragma unroll
      for (int gg=1;gg<NG;gg++){ unsigned x = (unsigned)(g[gg]>>32); nl = (x<nl)?x:nl; }
      lmin = nl;
    }
  }
}

__global__ void k_dirs_soa(const float* __restrict__ vbcs, int V,
                           const int* __restrict__ idx, float* __restrict__ dirs,
                           int total){
  int id = blockIdx.x*256 + threadIdx.x;
  if (id >= total) return;
  int v = (id/20) % V, b = id/(20*V);
  const float* vx = vbcs + (size_t)b*3*V;
  const float* vy = vx + V;
  const float* vz = vy + V;
  int nb = idx[id];
  float dx = vx[nb]-vx[v];
  float dy = vy[nb]-vy[v];
  float dz = vz[nb]-vz[v];
  float s = 1.f / fmaxf(sqrtf(dx*dx+dy*dy+dz*dz), 1e-12f);
  dirs[(size_t)id*3+0]=dx*s; dirs[(size_t)id*3+1]=dy*s; dirs[(size_t)id*3+2]=dz*s;
}

__global__ void k_surf4(const float* __restrict__ dirs, const float* __restrict__ dir0,
                        ushort* __restrict__ fh, int V){
  int id = blockIdx.x*256 + threadIdx.x;
  if (id >= BB*V*8) return;
  int k4 = (id & 7)*4; int vv = (id>>3) % V; int b = id/(8*V);
  f4v nx = *(const f4v*)&dir0[k4];
  f4v ny = *(const f4v*)&dir0[32+k4];
  f4v nz = *(const f4v*)&dir0[64+k4];
  #pragma unroll
  for (int j=0;j<4;j++){
    float s = 1.f/fmaxf(sqrtf(nx[j]*nx[j]+ny[j]*ny[j]+nz[j]*nz[j]), 1e-12f);
    nx[j]*=s; ny[j]*=s; nz[j]*=s;
  }
  const float* dd = dirs + (size_t)(b*V+vv)*60;
  f4v m = (f4v){0.f,0.f,0.f,0.f};
  for (int n=0;n<20;n++){
    float d0=dd[n*3], d1=dd[n*3+1], d2=dd[n*3+2];
    #pragma unroll
    for (int j=0;j<4;j++){
      float th = d0*nx[j] + d1*ny[j] + d2*nz[j];
      m[j] = fmaxf(m[j], fmaxf(th, 0.f));
    }
  }
  size_t p = (size_t)(b*V+vv)*32 + k4;
  #pragma unroll
  for (int j=0;j<4;j++) fh[p+j] = f2bf(m[j]);
}

template<int OUT>
__global__ void k_comb4(const float* __restrict__ feat, const int* __restrict__ idx,
                        const float* __restrict__ dirs, const float* __restrict__ dw,
                        float* __restrict__ outp, ushort* __restrict__ oh,
                        int V, int OC, int relu_flag){
  int id = blockIdx.x*256 + threadIdx.x;
  int OC4 = OC>>2;
  if (id >= BB*V*OC4) return;
  int o4 = (id % OC4)*4, v = (id/OC4) % V, b = id/(OC4*V);
  f4v wx = *(const f4v*)&dw[o4];
  f4v wy = *(const f4v*)&dw[OC+o4];
  f4v wz = *(const f4v*)&dw[2*OC+o4];
  #pragma unroll
  for (int j=0;j<4;j++){
    float s = 1.f/fmaxf(sqrtf(wx[j]*wx[j]+wy[j]*wy[j]+wz[j]*wz[j]), 1e-12f);
    wx[j]*=s; wy[j]*=s; wz[j]*=s;
  }
  size_t row = (size_t)b*V + v;
  const int* ir = idx + row*20;
  const float* dd = dirs + row*60;
  f4v center = *(const f4v*)&feat[row*2*OC + o4];
  f4v m = (f4v){-INFINITY,-INFINITY,-INFINITY,-INFINITY};
  for (int n=0;n<20;n++){
    int nb = ir[n];
    float d0=dd[n*3], d1=dd[n*3+1], d2=dd[n*3+2];
    f4v sup = *(const f4v*)&feat[((size_t)b*V + nb)*2*OC + OC + o4];
    #pragma unroll
    for (int j=0;j<4;j++){
      float th = fmaxf(d0*wx[j] + d1*wy[j] + d2*wz[j], 0.f);
      m[j] = fmaxf(m[j], th*sup[j]);
    }
  }
  if (OUT == 0){
    f4v rv;
    #pragma unroll
    for (int j=0;j<4;j++){
      float x = center[j] + m[j];
      rv[j] = relu_flag ? fmaxf(x, 0.f) : x;
    }
    *(f4v*)&outp[row*OC + o4] = rv;
  } else {
    #pragma unroll
    for (int j=0;j<4;j++)
      oh[row*OC + o4 + j] = f2bf(fmaxf(center[j] + m[j], 0.f));
  }
}

template<int OUT>
__global__ void k_pool(const float* __restrict__ fm, const int* __restrict__ idxsrc,
                       const int* __restrict__ perm,
                       float* __restrict__ outp, ushort* __restrict__ oh,
                       int V, int C, int numS){
  int id = blockIdx.x*256 + threadIdx.x;
  if (id >= BB*numS*C) return;
  int c = id % C, sI = (id/C) % numS, b = id/(C*numS);
  const int* ir = idxsrc + ((size_t)b*V + perm[sI])*20;
  float m = -INFINITY;
  for (int n=0;n<4;n++) m = fmaxf(m, fm[((size_t)b*V + ir[n])*C + c]);
  size_t p = ((size_t)b*numS + sI)*C + c;
  if (OUT == 0) outp[p] = m;
  else oh[p] = f2bf(m);
}

__global__ void k_vgather(const float* __restrict__ vsrc, const int* __restrict__ perm,
                          float* __restrict__ vbcs, int V, int numS){
  int id = blockIdx.x*256 + threadIdx.x;
  if (id >= BB*3*numS) return;
  int s = id % numS, c = (id/numS) % 3, b = id/(3*numS);
  vbcs[id] = vsrc[((size_t)b*3 + c)*V + perm[s]];
}

__global__ void k_colmax(const float* __restrict__ x, float* __restrict__ o, int Vr, int C){
  int id = blockIdx.x*256 + threadIdx.x;
  if (id >= BB*C) return;
  int c = id % C, b = id / C;
  float m = -INFINITY;
  for (int v=0; v<Vr; v++) m = fmaxf(m, x[(size_t)(b*Vr+v)*C + c]);
  o[id] = m;
}

/* ---------------- FC head ---------------- */

// fused embedding + h (homogeneous wave-per-output dot products)
__global__ __launch_bounds__(256) void k_embh(const float* __restrict__ xmax, const float* __restrict__ fg,
                                              const float* __restrict__ fcw, const float* __restrict__ fcb,
                                              const float* __restrict__ clw1, const float* __restrict__ clb1,
                                              const float* __restrict__ gamma, const float* __restrict__ beta,
                                              float* __restrict__ outp, float* __restrict__ h){
  int gid = blockIdx.x*4 + (threadIdx.x>>6);
  int lane = threadIdx.x & 63;
  if (gid >= 2*BB*512) return;
  bool isH = gid >= BB*512;
  int g2 = isH ? gid - BB*512 : gid;
  int e = g2 & 511, b = g2 >> 9;
  const float* wr = (isH ? clw1 : fcw) + (size_t)e*2048;
  const float* xb = xmax + b*1024;
  const float* gb = fg + b*1024;
  float acc = 0.f;
  for (int k=lane; k<1024; k+=64)
    acc += xb[k]*wr[k] + gb[k]*wr[1024+k];
  #pragma unroll
  for (int off=32; off>0; off>>=1) acc += __shfl_xor(acc, off, 64);
  if (lane==0){
    if (isH){
      const float inv_s = 1.0f / sqrtf(1.0f + 1e-5f);
      float v = (acc + clb1[e]) * inv_s * gamma[e] + beta[e];
      h[g2] = fmaxf(v, 0.f);
    } else {
      outp[g2] = acc + fcb[e];
    }
  }
}

__global__ __launch_bounds__(256) void k_pred2(const float* __restrict__ h, const float* __restrict__ clw2,
                                               const float* __restrict__ clb2, float* __restrict__ outp){
  int gid = blockIdx.x*4 + (threadIdx.x>>6);
  int lane = threadIdx.x & 63;
  if (gid >= BB*6) return;
  int o = gid % 6, b = gid / 6;
  const float* hb = h + b*512;
  const float* wr = clw2 + o*512;
  float acc = 0.f;
  for (int k=lane; k<512; k+=64) acc += hb[k]*wr[k];
  #pragma unroll
  for (int off=32; off>0; off>>=1) acc += __shfl_xor(acc, off, 64);
  if (lane==0) outp[BB*512 + gid] = acc + clb2[o];
}

/* ---------------- launch ---------------- */

static inline int cdiv(long long a, int b){ return (int)((a + b - 1)/b); }

extern "C" void kernel_launch(void* const* d_in, const int* in_sizes, int n_in,
                              void* d_out, int out_size, void* d_ws, size_t ws_size,
                              hipStream_t stream){
  float* out = (float*)d_out;
  if (n_in != 30 || in_sizes[0] != BB*3*NN || out_size != BB*512 + BB*6){
    k_sentinel<<<cdiv(out_size,256),256,0,stream>>>(out, out_size, 2000.0f);
    return;
  }
  const float* xyz  = (const float*)d_in[0];
  const float* w1   = (const float*)d_in[1];
  const float* b1   = (const float*)d_in[2];
  const float* w2   = (const float*)d_in[3];
  const float* b2   = (const float*)d_in[4];
  const float* w3   = (const float*)d_in[5];
  const float* b3   = (const float*)d_in[6];
  const float* w4   = (const float*)d_in[7];
  const float* b4   = (const float*)d_in[8];
  const float* fcw  = (const float*)d_in[9];
  const float* fcb  = (const float*)d_in[10];
  const float* dir0 = (const float*)d_in[11];
  const float* wc1  = (const float*)d_in[12];
  const float* bc1  = (const float*)d_in[13];
  const float* dir1 = (const float*)d_in[14];
  const float* wc2  = (const float*)d_in[15];
  const float* bc2  = (const float*)d_in[16];
  const float* dir2 = (const float*)d_in[17];
  const float* wc3  = (const float*)d_in[18];
  const float* bc3  = (const float*)d_in[19];
  const float* dir3 = (const float*)d_in[20];
  const float* wc4  = (const float*)d_in[21];
  const float* bc4  = (const float*)d_in[22];
  const float* dir4 = (const float*)d_in[23];
  const float* clw1 = (const float*)d_in[24];
  const float* clb1 = (const float*)d_in[25];
  const float* gma  = (const float*)d_in[26];
  const float* bta  = (const float*)d_in[27];
  const float* clw2 = (const float*)d_in[28];
  const float* clb2 = (const float*)d_in[29];

  char* w = (char*)d_ws;
  size_t off = 0;
  auto A = [&](size_t bytes){ size_t r = off; off += (bytes + 255) & ~(size_t)255; return r; };
  const size_t oXMAX = A((size_t)BB*1024*4);
  const size_t oFG   = A((size_t)BB*1024*4);
  const size_t oGFP  = A((size_t)BB*128*2*2);
  const size_t oH    = A((size_t)BB*512*4);
  const size_t oP2048= A(2048*4);
  const size_t oP512 = A(512*4);
  const size_t oPK1  = A(2048*4);
  const size_t oPK2  = A(2048*4);
  const size_t oPK3  = A(512*4);
  const size_t oPA   = A(2048*4);
  const size_t oPMAX = A((size_t)BB*1024*32*4);
  const size_t oV1S  = A((size_t)BB*3*512*4);
  const size_t oV2S  = A((size_t)BB*3*128*4);
  const size_t oIDX0 = A((size_t)BB*2048*20*4);   // aliased by x2T planes (dead before knn)
  const size_t oDIR0 = A((size_t)BB*2048*20*3*4);
  const size_t oFM0  = A((size_t)BB*2048*32*2);   // hi only
  const size_t oFM1  = A((size_t)BB*2048*64*4);
  const size_t oFM1P = A((size_t)BB*512*64*2);
  const size_t oIDX1 = A((size_t)BB*512*20*4);
  const size_t oDIR1 = A((size_t)BB*512*20*3*4);
  const size_t oFM2  = A((size_t)BB*512*128*2);
  const size_t oFM3  = A((size_t)BB*512*256*4);
  const size_t oFM3P = A((size_t)BB*128*256*2);
  const size_t oIDX2 = A((size_t)BB*128*20*4);
  const size_t oDIR2 = A((size_t)BB*128*20*3*4);
  const size_t oFM4  = A((size_t)BB*128*1024*4);
  const size_t oBIGA = A((size_t)BB*256*NN*4);    // x1T planes then x3T planes
  const size_t oBIGB = A((size_t)BB*128*NN*4);    // feat f32
  const size_t oW2P  = A((size_t)128*64*2);
  const size_t oW3P  = A((size_t)256*256*2);
  const size_t oW4P  = A((size_t)1024*256*2);
  const size_t oWC1T = A((size_t)32*128*2*2);
  const size_t oWC2T = A((size_t)64*256*2*2);
  const size_t oWC3T = A((size_t)128*512*2*2);
  const size_t oWC4T = A((size_t)256*2048*2*2);
  if (off > ws_size){
    k_sentinel<<<cdiv(out_size,256),256,0,stream>>>(out, out_size, 1000.0f);
    return;
  }
  float* xmax = (float*)(w+oXMAX); float* fg = (float*)(w+oFG);
  float* hbuf = (float*)(w+oH);
  ushort* gfh = (ushort*)(w+oGFP); ushort* gfl = gfh + BB*128;
  int* p2048 = (int*)(w+oP2048);   int* p512 = (int*)(w+oP512);
  unsigned* pk1 = (unsigned*)(w+oPK1); unsigned* pk2 = (unsigned*)(w+oPK2);
  unsigned* pk3 = (unsigned*)(w+oPK3); int* pa = (int*)(w+oPA);
  float* pmax = (float*)(w+oPMAX);
  float* v1s = (float*)(w+oV1S); float* v2s = (float*)(w+oV2S);
  int* idx0 = (int*)(w+oIDX0); int* idx1 = (int*)(w+oIDX1); int* idx2 = (int*)(w+oIDX2);
  float* d0 = (float*)(w+oDIR0); float* d1 = (float*)(w+oDIR1); float* d2 = (float*)(w+oDIR2);
  ushort* fm0h = (ushort*)(w+oFM0);
  float* fm1 = (float*)(w+oFM1);
  ushort* fm1ph = (ushort*)(w+oFM1P);
  ushort* fm2h = (ushort*)(w+oFM2);
  float* fm3 = (float*)(w+oFM3);
  ushort* fm3ph = (ushort*)(w+oFM3P);
  float* fm4 = (float*)(w+oFM4);
  ushort* x1h = (ushort*)(w+oBIGA); ushort* x1l = x1h + (size_t)BB*2048*64;
  ushort* x3h = (ushort*)(w+oBIGA); ushort* x3l = x3h + (size_t)BB*2048*256;
  ushort* x2h = (ushort*)(w+oIDX0); ushort* x2l = x2h + (size_t)BB*2048*128;
  float* feat = (float*)(w+oBIGB);
  ushort* w2ph = (ushort*)(w+oW2P);
  ushort* w3ph = (ushort*)(w+oW3P);
  ushort* w4ph = (ushort*)(w+oW4P);
  ushort* wc1h = (ushort*)(w+oWC1T); ushort* wc1l = wc1h + 32*128;
  ushort* wc2h = (ushort*)(w+oWC2T); ushort* wc2l = wc2h + 64*256;
  ushort* wc3h = (ushort*)(w+oWC3T); ushort* wc3l = wc3h + 128*512;
  ushort* wc4h = (ushort*)(w+oWC4T); ushort* wc4l = wc4h + 256*2048;

  // weight pre-split
  k_wsplit3h<<<cdiv(128*64+256*256+1024*256,256),256,0,stream>>>(
      w2, w2ph, 128*64,  w3, w3ph, 256*256,  w4, w4ph, 1024*256);
  k_wstr4<<<cdiv(32*128+64*256+128*512+256*2048,256),256,0,stream>>>(
      wc1, wc1h, wc1l, 32, 128,  wc2, wc2h, wc2l, 64, 256,
      wc3, wc3h, wc3l, 128, 512, wc4, wc4h, wc4l, 256, 2048);

  // MLP branch
  k_mlp1s<<<cdiv((long long)BB*NN*64,256),256,0,stream>>>(xyz, w1, b1, x1h, x1l);
  k_bgemm<4,1,0><<<dim3(32,1,BB),256,0,stream>>>(w2ph, x1h, x1l, nullptr, nullptr,
      b2, nullptr, pmax, x2h, x2l, 64, 64, 64, 2048, (size_t)2048*64, 0, 128);
  k_gmax<<<cdiv(BB*128,256),256,0,stream>>>(pmax, gfh, gfl, 32, BB*128);
  k_bgemm<3,1,0><<<dim3(32,2,BB),256,0,stream>>>(w3ph, x2h, x2l, gfh, gfl,
      b3, nullptr, nullptr, x3h, x3l, 256, 128, 128, 2048, (size_t)2048*128, 0, 256);
  k_bgemm<1,1,0><<<dim3(32,8,BB),256,0,stream>>>(w4ph, x3h, x3l, nullptr, nullptr,
      b4, nullptr, pmax, nullptr, nullptr, 256, 256, 256, 2048, (size_t)2048*256, 0, 1024);
  k_xmax<<<cdiv(BB*1024,256),256,0,stream>>>(pmax, xmax);

  // permutations
  {
    unsigned ck0=0u, ck1=1u, nk0,nk1, s00,s01, s10,s11, sc0,sc1;
    tf2h(ck0,ck1, 0u,0u, nk0,nk1);
    tf2h(ck0,ck1, 0u,1u, s00,s01);
    tf2h(nk0,nk1, 0u,1u, s10,s11);
    tf2h(0u,2u,  0u,1u, sc0,sc1);
    k_permkeys3<<<8,256,0,stream>>>(s00,s01,pk1, s10,s11,pk2, sc0,sc1,pk3);
    k_permrank<<<8,256,0,stream>>>(2048, pk1, nullptr, pa);
    k_permrank<<<8,256,0,stream>>>(2048, pk2, pa, p2048);
    k_permrank<<<2,256,0,stream>>>(512, pk3, nullptr, p512);
  }

  // graph branch: stage 0 (V=2048)
  k_knn_s<32,20><<<dim3(512,BB),256,0,stream>>>(xyz, 2048, idx0);
  k_dirs_soa<<<cdiv((long long)BB*2048*20,256),256,0,stream>>>(xyz, 2048, idx0, d0, BB*2048*20);
  k_surf4<<<cdiv((long long)BB*2048*8,256),256,0,stream>>>(d0, dir0, fm0h, 2048);
  k_bgemm<0,0,1><<<dim3(2,256,1),256,0,stream>>>(fm0h, wc1h, wc1l, nullptr, nullptr,
      bc1, feat, nullptr, nullptr, nullptr, 32, 32, 32, 128, 0, 0, BB*2048);
  k_comb4<0><<<cdiv((long long)BB*2048*16,256),256,0,stream>>>(feat, idx0, d0, dir1, fm1, nullptr, 2048, 64, 1);
  // pool 1 (prefix-index inlined)
  k_pool<1><<<cdiv((long long)BB*512*64,256),256,0,stream>>>(fm1, idx0, p2048, nullptr, fm1ph, 2048, 64, 512);
  k_vgather<<<cdiv((long long)BB*3*512,256),256,0,stream>>>(xyz, p2048, v1s, 2048, 512);
  // stage 1 (V=512)
  k_knn_s<8,20><<<dim3(128,BB),256,0,stream>>>(v1s, 512, idx1);
  k_dirs_soa<<<cdiv((long long)BB*512*20,256),256,0,stream>>>(v1s, 512, idx1, d1, BB*512*20);
  k_bgemm<0,0,1><<<dim3(4,64,1),256,0,stream>>>(fm1ph, wc2h, wc2l, nullptr, nullptr,
      bc2, feat, nullptr, nullptr, nullptr, 64, 64, 64, 256, 0, 0, BB*512);
  k_comb4<1><<<cdiv((long long)BB*512*32,256),256,0,stream>>>(feat, idx1, d1, dir2, nullptr, fm2h, 512, 128, 1);
  k_bgemm<0,0,1><<<dim3(8,64,1),256,0,stream>>>(fm2h, wc3h, wc3l, nullptr, nullptr,
      bc3, feat, nullptr, nullptr, nullptr, 128, 128, 128, 512, 0, 0, BB*512);
  k_comb4<0><<<cdiv((long long)BB*512*64,256),256,0,stream>>>(feat, idx1, d1, dir3, fm3, nullptr, 512, 256, 1);
  // pool 2 (prefix-index inlined)
  k_pool<1><<<cdiv((long long)BB*128*256,256),256,0,stream>>>(fm3, idx1, p512, nullptr, fm3ph, 512, 256, 128);
  k_vgather<<<cdiv((long long)BB*3*128,256),256,0,stream>>>(v1s, p512, v2s, 512, 128);
  // stage 2 (V=128)
  k_knn_s<2,20><<<dim3(32,BB),256,0,stream>>>(v2s, 128, idx2);
  k_dirs_soa<<<cdiv((long long)BB*128*20,256),256,0,stream>>>(v2s, 128, idx2, d2, BB*128*20);
  k_bgemm<0,0,1><<<dim3(32,16,1),256,0,stream>>>(fm3ph, wc4h, wc4l, nullptr, nullptr,
      bc4, feat, nullptr, nullptr, nullptr, 256, 256, 256, 2048, 0, 0, BB*128);
  k_comb4<0><<<cdiv((long long)BB*128*256,256),256,0,stream>>>(feat, idx2, d2, dir4, fm4, nullptr, 128, 1024, 0);
  k_colmax<<<cdiv(BB*1024,256),256,0,stream>>>(fm4, fg, 128, 1024);

  // FC head
  k_embh<<<cdiv(2*BB*512,4),256,0,stream>>>(xmax, fg, fcw, fcb, clw1, clb1, gma, bta, out, hbuf);
  k_pred2<<<cdiv(BB*6,4),256,0,stream>>>(hbuf, clw2, clb2, out);
}